// Round 1
// baseline (831.907 us; speedup 1.0000x reference)
//
#include <hip/hip_runtime.h>
#include <cstdint>

#define N_ANCH 8400
#define WMAX 132   // ceil(8400/64)

__device__ __forceinline__ uint64_t readlane64(uint64_t v, int lane) {
  unsigned lo = (unsigned)__builtin_amdgcn_readlane((int)(unsigned)(v & 0xffffffffull), lane);
  unsigned hi = (unsigned)__builtin_amdgcn_readlane((int)(unsigned)(v >> 32), lane);
  return ((uint64_t)hi << 32) | lo;
}
__device__ __forceinline__ uint64_t firstlane64(uint64_t v) {
  unsigned lo = (unsigned)__builtin_amdgcn_readfirstlane((int)(unsigned)(v & 0xffffffffull));
  unsigned hi = (unsigned)__builtin_amdgcn_readfirstlane((int)(unsigned)(v >> 32));
  return ((uint64_t)hi << 32) | lo;
}

// Kernel A: exact stable rank (descending score, invalid -> -inf, ties by index),
// scatter boxes/scores into sorted order, count valid.
__global__ __launch_bounds__(256) void k_rank(const float* __restrict__ in,
                                              float* __restrict__ scores_s,
                                              float4* __restrict__ boxes_s,
                                              unsigned* __restrict__ nvp) {
  __shared__ alignas(16) float sc[N_ANCH];
  __shared__ int part[256];
  const int tid = threadIdx.x;
  const float* srow = in + 4 * N_ANCH;
  for (int j = tid; j < N_ANCH; j += 256) sc[j] = srow[j];
  __syncthreads();
  const int il = tid & 63, q = tid >> 6;
  const int i = blockIdx.x * 64 + il;
  const float si = (i < N_ANCH) ? sc[i] : 0.0f;
  const bool valid = si > 0.5f;
  const float key = valid ? si : -INFINITY;
  int cnt = 0;
  const float4* sc4 = (const float4*)sc;
  const int jb = q * (N_ANCH / 4);  // 2100 floats per quarter
  for (int jj = 0; jj < (N_ANCH / 16); ++jj) {  // 525 float4 per quarter
    float4 v = sc4[q * (N_ANCH / 16) + jj];
    int j0 = jb + jj * 4;
    float k0 = (v.x > 0.5f) ? v.x : -INFINITY;
    float k1 = (v.y > 0.5f) ? v.y : -INFINITY;
    float k2 = (v.z > 0.5f) ? v.z : -INFINITY;
    float k3 = (v.w > 0.5f) ? v.w : -INFINITY;
    cnt += (k0 > key) || (k0 == key && (j0 + 0) < i);
    cnt += (k1 > key) || (k1 == key && (j0 + 1) < i);
    cnt += (k2 > key) || (k2 == key && (j0 + 2) < i);
    cnt += (k3 > key) || (k3 == key && (j0 + 3) < i);
  }
  part[tid] = cnt;
  __syncthreads();
  if (q == 0 && i < N_ANCH) {
    int r = part[il] + part[64 + il] + part[128 + il] + part[192 + il];
    float cx = in[0 * N_ANCH + i], cy = in[1 * N_ANCH + i];
    float w  = in[2 * N_ANCH + i], h  = in[3 * N_ANCH + i];
    float x1 = cx - w * 0.5f, y1 = cy - h * 0.5f;
    float x2 = cx + w * 0.5f, y2 = cy + h * 0.5f;
    boxes_s[r] = make_float4(x1, y1, x2, y2);
    scores_s[r] = valid ? si : 0.0f;
    if (valid) atomicAdd(nvp, 1u);
  }
}

// Kernel B: symmetric suppression bitmask sup[i][w] over the valid sorted prefix.
// Bit l of word w: IoU(box_i, box_{64w+l}) > 0.5 (exact reference float semantics).
__global__ __launch_bounds__(256) void k_sup(const float4* __restrict__ boxes_s,
                                             const unsigned* __restrict__ nvp,
                                             unsigned long long* __restrict__ sup) {
  const int nv = (int)*nvp;
  const int W = (nv + 63) >> 6;
  const int w = blockIdx.x;
  if (w >= W) return;
  __shared__ float bx1[64], by1[64], bx2[64], by2[64], bar[64];
  const int tid = threadIdx.x;
  if (tid < 64) {
    int j = w * 64 + tid;
    float4 b = (j < N_ANCH) ? boxes_s[j] : make_float4(0.f, 0.f, 0.f, 0.f);
    bx1[tid] = b.x; by1[tid] = b.y; bx2[tid] = b.z; by2[tid] = b.w;
    bar[tid] = (b.z - b.x) * (b.w - b.y);
  }
  __syncthreads();
  const int i = blockIdx.y * 256 + tid;
  if (i >= nv) return;
  float4 bi = boxes_s[i];
  float ai = (bi.z - bi.x) * (bi.w - bi.y);
  const int jmax = nv - w * 64;  // bits l < jmax are in-range
  uint64_t bits = 0;
  #pragma unroll 8
  for (int l = 0; l < 64; ++l) {
    float lx = fmaxf(bi.x, bx1[l]);
    float ly = fmaxf(bi.y, by1[l]);
    float rx = fminf(bi.z, bx2[l]);
    float ry = fminf(bi.w, by2[l]);
    float dx = fmaxf(rx - lx, 0.0f);
    float dy = fmaxf(ry - ly, 0.0f);
    float inter = dx * dy;
    asm volatile("" : "+v"(inter));           // block fma-contraction into union
    float uni = (ai + bar[l]) - inter;        // reference op order
    float iou = inter / uni;                  // IEEE f32 div, matches numpy
    bits |= ((uint64_t)((l < jmax) && (iou > 0.5f))) << l;
  }
  sup[(size_t)i * W + w] = bits;
}

// Kernel C: single-workgroup blocked greedy scan (exact Gauss-Seidel order),
// then write all 8400x5 outputs.
__global__ __launch_bounds__(256) void k_scan_out(const float* __restrict__ scores_s,
                                                  const float4* __restrict__ boxes_s,
                                                  const unsigned long long* __restrict__ sup,
                                                  const unsigned* __restrict__ nvp,
                                                  float* __restrict__ out) {
  __shared__ uint64_t keep[WMAX];
  const int tid = threadIdx.x;
  const int nv = (int)*nvp;
  const int W = (nv + 63) >> 6;
  if (tid < WMAX) {
    uint64_t v = 0;
    int base = tid * 64;
    if (base < nv) {
      int rem = nv - base;
      v = (rem >= 64) ? ~0ull : ((1ull << rem) - 1ull);
    }
    keep[tid] = v;
  }
  __syncthreads();

  for (int k = 0; k < W; ++k) {
    // --- resolve 64x64 diagonal block: pure scalar chain, readlanes hoistable ---
    if (tid < 64) {
      int c = k * 64 + tid;
      uint64_t dw = (c < nv) ? (uint64_t)sup[(size_t)c * W + k] : 0ull;
      uint64_t bk = firstlane64(keep[k]);
      #pragma unroll
      for (int r = 0; r < 64; ++r) {
        uint64_t sr = readlane64(dw, r);
        uint64_t m = sr & ~((2ull << r) - 1ull);   // columns strictly > r
        bk &= ~(((bk >> r) & 1ull) ? m : 0ull);
      }
      if (tid == 0) keep[k] = bk;
    }
    __syncthreads();
    // --- apply block's kept rows to all later keep-words ---
    uint64_t bk2 = firstlane64(keep[k]);
    const int rowbase = k * 64;
    for (int w = k + 1 + tid; w < W; w += 256) {
      uint64_t acc = 0;
      #pragma unroll
      for (int r8 = 0; r8 < 8; ++r8) {
        unsigned byte = (unsigned)((bk2 >> (r8 * 8)) & 0xffull);
        if (byte) {
          #pragma unroll
          for (int r = 0; r < 8; ++r) {
            int row = rowbase + r8 * 8 + r;
            row = (row < nv) ? row : (nv - 1);   // stay in initialized rows
            uint64_t mrow = (uint64_t)sup[(size_t)row * W + w];
            acc |= mrow & (0ull - (uint64_t)((byte >> r) & 1u));
          }
        }
      }
      keep[w] &= ~acc;
    }
    __syncthreads();
  }

  // --- emit output: kept rows get (x1,y1,x2,y2,score), else zeros ---
  for (int r = tid; r < N_ANCH; r += 256) {
    bool kept = (r < nv) && ((keep[r >> 6] >> (r & 63)) & 1ull);
    float4 b = kept ? boxes_s[r] : make_float4(0.f, 0.f, 0.f, 0.f);
    float s = kept ? scores_s[r] : 0.0f;
    out[r * 5 + 0] = b.x;
    out[r * 5 + 1] = b.y;
    out[r * 5 + 2] = b.z;
    out[r * 5 + 3] = b.w;
    out[r * 5 + 4] = s;
  }
}

extern "C" void kernel_launch(void* const* d_in, const int* in_sizes, int n_in,
                              void* d_out, int out_size, void* d_ws, size_t ws_size,
                              hipStream_t stream) {
  const float* in = (const float*)d_in[0];
  float* out = (float*)d_out;
  uint8_t* ws = (uint8_t*)d_ws;
  unsigned* nvp = (unsigned*)ws;                                   // [0,64)
  float* scores_s = (float*)(ws + 64);                             // 33600 B
  float4* boxes_s = (float4*)(ws + 64 + 33600);                    // 134400 B (16-aligned)
  unsigned long long* sup = (unsigned long long*)(ws + 64 + 33600 + 134400);  // ~nv^2/8 B

  hipMemsetAsync(ws, 0, 64, stream);
  k_rank<<<dim3(WMAX), dim3(256), 0, stream>>>(in, scores_s, boxes_s, nvp);
  k_sup<<<dim3(WMAX, (N_ANCH + 255) / 256), dim3(256), 0, stream>>>(boxes_s, nvp, sup);
  k_scan_out<<<dim3(1), dim3(256), 0, stream>>>(scores_s, boxes_s, sup, nvp, out);
}

// Round 2
// 340.684 us; speedup vs baseline: 2.4419x; 2.4419x over previous
//
#include <hip/hip_runtime.h>
#include <cstdint>

#define N_ANCH 8400
#define WMAX   132          // ceil(8400/64)
#define NT     128          // k_scan_out threads (2 waves)
#define PAN_WCAP 88         // panel supports W <= 88 (nv <= 5632; actual nv ~ 4200 -> W ~ 66)
#define PAN_WORDS (64 * PAN_WCAP)   // 5632 u64 per slot = 45056 B
#define NI     22           // fixed global_load_lds issues per wave per panel: 22*128*16B = 45056 B

__device__ __forceinline__ uint64_t readlane64(uint64_t v, int lane) {
  unsigned lo = (unsigned)__builtin_amdgcn_readlane((int)(unsigned)(v & 0xffffffffull), lane);
  unsigned hi = (unsigned)__builtin_amdgcn_readlane((int)(unsigned)(v >> 32), lane);
  return ((uint64_t)hi << 32) | lo;
}

__device__ __forceinline__ void gl16(const void* g, void* l) {
  __builtin_amdgcn_global_load_lds((const __attribute__((address_space(1))) uint32_t*)g,
                                   (__attribute__((address_space(3))) uint32_t*)l, 16, 0, 0);
}

// Kernel A: exact stable rank (descending score, invalid -> -inf, ties by index),
// scatter boxes/scores into sorted order, count valid.
__global__ __launch_bounds__(256) void k_rank(const float* __restrict__ in,
                                              float* __restrict__ scores_s,
                                              float4* __restrict__ boxes_s,
                                              unsigned* __restrict__ nvp) {
  __shared__ alignas(16) float sc[N_ANCH];
  __shared__ int part[256];
  const int tid = threadIdx.x;
  const float* srow = in + 4 * N_ANCH;
  for (int j = tid; j < N_ANCH; j += 256) sc[j] = srow[j];
  __syncthreads();
  const int il = tid & 63, q = tid >> 6;
  const int i = blockIdx.x * 64 + il;
  const float si = (i < N_ANCH) ? sc[i] : 0.0f;
  const bool valid = si > 0.5f;
  const float key = valid ? si : -INFINITY;
  int cnt = 0;
  const float4* sc4 = (const float4*)sc;
  const int jb = q * (N_ANCH / 4);
  for (int jj = 0; jj < (N_ANCH / 16); ++jj) {
    float4 v = sc4[q * (N_ANCH / 16) + jj];
    int j0 = jb + jj * 4;
    float k0 = (v.x > 0.5f) ? v.x : -INFINITY;
    float k1 = (v.y > 0.5f) ? v.y : -INFINITY;
    float k2 = (v.z > 0.5f) ? v.z : -INFINITY;
    float k3 = (v.w > 0.5f) ? v.w : -INFINITY;
    cnt += (k0 > key) || (k0 == key && (j0 + 0) < i);
    cnt += (k1 > key) || (k1 == key && (j0 + 1) < i);
    cnt += (k2 > key) || (k2 == key && (j0 + 2) < i);
    cnt += (k3 > key) || (k3 == key && (j0 + 3) < i);
  }
  part[tid] = cnt;
  __syncthreads();
  if (q == 0 && i < N_ANCH) {
    int r = part[il] + part[64 + il] + part[128 + il] + part[192 + il];
    float cx = in[0 * N_ANCH + i], cy = in[1 * N_ANCH + i];
    float w  = in[2 * N_ANCH + i], h  = in[3 * N_ANCH + i];
    float x1 = cx - w * 0.5f, y1 = cy - h * 0.5f;
    float x2 = cx + w * 0.5f, y2 = cy + h * 0.5f;
    boxes_s[r] = make_float4(x1, y1, x2, y2);
    scores_s[r] = valid ? si : 0.0f;
    if (valid) atomicAdd(nvp, 1u);
  }
}

// Kernel B: suppression bits, COLUMN-BLOCK layout: sup2[w * Rpad + i] holds,
// for row i, bits l of word w: IoU(box_i, box_{64w+l}) > 0.5. Coalesced stores.
__global__ __launch_bounds__(256) void k_sup(const float4* __restrict__ boxes_s,
                                             const unsigned* __restrict__ nvp,
                                             unsigned long long* __restrict__ sup2) {
  const int nv = (int)*nvp;
  const int W = (nv + 63) >> 6;
  const int Rpad = W << 6;
  const int w = blockIdx.x;
  if (w >= W) return;
  __shared__ float bx1[64], by1[64], bx2[64], by2[64], bar[64];
  const int tid = threadIdx.x;
  if (tid < 64) {
    int j = w * 64 + tid;
    float4 b = (j < N_ANCH) ? boxes_s[j] : make_float4(0.f, 0.f, 0.f, 0.f);
    bx1[tid] = b.x; by1[tid] = b.y; bx2[tid] = b.z; by2[tid] = b.w;
    bar[tid] = (b.z - b.x) * (b.w - b.y);
  }
  __syncthreads();
  const int i = blockIdx.y * 256 + tid;
  if (i >= nv) return;
  float4 bi = boxes_s[i];
  float ai = (bi.z - bi.x) * (bi.w - bi.y);
  const int jmax = nv - w * 64;
  uint64_t bits = 0;
  #pragma unroll 8
  for (int l = 0; l < 64; ++l) {
    float lx = fmaxf(bi.x, bx1[l]);
    float ly = fmaxf(bi.y, by1[l]);
    float rx = fminf(bi.z, bx2[l]);
    float ry = fminf(bi.w, by2[l]);
    float dx = fmaxf(rx - lx, 0.0f);
    float dy = fmaxf(ry - ly, 0.0f);
    float inter = dx * dy;
    asm volatile("" : "+v"(inter));           // block fma-contraction into union
    float uni = (ai + bar[l]) - inter;        // reference op order
    float iou = inter / uni;                  // IEEE f32 div, matches numpy
    bits |= ((uint64_t)((l < jmax) && (iou > 0.5f))) << l;
  }
  sup2[(size_t)w * Rpad + i] = bits;
}

// Kernel C: single-workgroup blocked greedy scan, panels staged in LDS via
// global_load_lds, pipeline depth 2 with counted vmcnt (never 0 mid-loop).
__global__ __launch_bounds__(NT) void k_scan_out(const float* __restrict__ scores_s,
                                                 const float4* __restrict__ boxes_s,
                                                 const unsigned long long* __restrict__ sup2_,
                                                 const unsigned* __restrict__ nvp,
                                                 float* __restrict__ out) {
  __shared__ uint64_t pan[3][PAN_WORDS];   // 135168 B
  __shared__ uint64_t keep_s[WMAX];        // 1056 B
  __shared__ uint64_t dummy_s[NT * 2];     // 2048 B dummy DMA target
  const uint64_t* sup2 = (const uint64_t*)sup2_;
  const int tid = threadIdx.x;
  const int nv = (int)*nvp;
  const int W  = (nv + 63) >> 6;
  const int Rpad = W << 6;

  for (int idx = tid; idx < WMAX; idx += NT) {
    uint64_t v = 0; int base = idx * 64;
    if (base < nv) { int rem = nv - base; v = (rem >= 64) ? ~0ull : ((1ull << rem) - 1ull); }
    keep_s[idx] = v;
  }

  // Panel layout for block kk, chunk c = wi-kk (0..W-kk): word (row, wi) lives at
  // pan[b][c*64 + (row ^ ((2c)&63))]. XOR swizzle spreads apply-phase banks;
  // chunk 0 (the diagonal word) is linear. LDS dst is linear (pre-swizzled src).
  auto issue_panel = [&](int kk, int b) {
    const int rowbase = kk * 64;
    const int totalPairs = (W - kk) * 32;        // 16B pairs
    uint8_t* pb = (uint8_t*)&pan[b][0];
    #pragma unroll 1
    for (int it = 0; it < NI; ++it) {
      int p = it * NT + tid;
      int pw0 = it * NT + (tid & ~63);           // wave-uniform first-lane pair idx
      if (pw0 >= totalPairs) {
        // keep per-wave vmcnt count fixed: dummy load, full exec
        gl16(sup2, (uint8_t*)dummy_s + ((tid >> 6) << 10));
      } else if (p < totalPairs) {
        int c = p >> 5;                          // 32 pairs per 64-word chunk
        int slot2 = (p & 31) << 1;               // even word slot in chunk
        int row = slot2 ^ ((2 * c) & 63);        // pre-swizzled source row (even)
        const uint64_t* g = sup2 + (size_t)(kk + c) * Rpad + rowbase + row;
        gl16(g, pb + (size_t)p * 16);
      }
    }
  };

  if (W > 0) issue_panel(0, 0);
  if (W > 1) issue_panel(1, 1);

  for (int k = 0; k < W; ++k) {
    const int slot = k % 3;
    // wait: panel k complete; panel k+1 (NI per wave) may stay in flight
    if (k + 1 < W) { asm volatile("s_waitcnt vmcnt(22) lgkmcnt(0)" ::: "memory"); }
    else           { asm volatile("s_waitcnt vmcnt(0) lgkmcnt(0)"  ::: "memory"); }
    __builtin_amdgcn_sched_barrier(0);
    __builtin_amdgcn_s_barrier();
    __builtin_amdgcn_sched_barrier(0);

    if (k + 2 < W) issue_panel(k + 2, (k + 2) % 3);

    // --- diagonal resolve: uniform ctz-skip chain over kept rows only ---
    if (tid < 64) {
      uint64_t dw = pan[slot][tid];              // row tid, word k (chunk 0, linear)
      uint64_t bk = keep_s[k];
      uint64_t cand = bk;
      while (cand) {
        int r = (int)__builtin_ctzll(cand);
        uint64_t sr = readlane64(dw, r);
        uint64_t m = sr & ~((2ull << r) - 1ull); // cols strictly > r (r=63 -> 0)
        cand &= ~(1ull << r);
        cand &= ~m;
        bk   &= ~m;
      }
      if (tid == 0) keep_s[k] = bk;
    }
    asm volatile("s_waitcnt lgkmcnt(0)" ::: "memory");
    __builtin_amdgcn_sched_barrier(0);
    __builtin_amdgcn_s_barrier();
    __builtin_amdgcn_sched_barrier(0);

    // --- apply kept rows of block k to all later keep-words (LDS only) ---
    uint64_t bk2 = keep_s[k];
    if (bk2) {
      for (int w2 = k + 1 + tid; w2 < W; w2 += NT) {
        int c  = w2 - k;
        int sx = (2 * c) & 63;
        int cb = c << 6;
        uint64_t acc = 0;
        uint64_t rem = bk2;
        while (rem) {
          int r = (int)__builtin_ctzll(rem);
          rem &= rem - 1;
          acc |= pan[slot][cb + (r ^ sx)];
        }
        keep_s[w2] &= ~acc;
      }
    }
    asm volatile("s_waitcnt lgkmcnt(0)" ::: "memory");
    __builtin_amdgcn_sched_barrier(0);
  }
  __syncthreads();

  // --- emit output ---
  for (int r = tid; r < N_ANCH; r += NT) {
    bool kept = (r < nv) && ((keep_s[r >> 6] >> (r & 63)) & 1ull);
    float4 b = kept ? boxes_s[r] : make_float4(0.f, 0.f, 0.f, 0.f);
    float s = kept ? scores_s[r] : 0.0f;
    out[r * 5 + 0] = b.x;
    out[r * 5 + 1] = b.y;
    out[r * 5 + 2] = b.z;
    out[r * 5 + 3] = b.w;
    out[r * 5 + 4] = s;
  }
}

extern "C" void kernel_launch(void* const* d_in, const int* in_sizes, int n_in,
                              void* d_out, int out_size, void* d_ws, size_t ws_size,
                              hipStream_t stream) {
  const float* in = (const float*)d_in[0];
  float* out = (float*)d_out;
  uint8_t* ws = (uint8_t*)d_ws;
  unsigned* nvp = (unsigned*)ws;                                   // [0,64)
  float* scores_s = (float*)(ws + 64);                             // 33600 B
  float4* boxes_s = (float4*)(ws + 64 + 33600);                    // 134400 B
  unsigned long long* sup2 = (unsigned long long*)(ws + 64 + 33600 + 134400);  // ~W*Rpad*8 ≈ 2.23 MB

  hipMemsetAsync(ws, 0, 64, stream);
  k_rank<<<dim3(WMAX), dim3(256), 0, stream>>>(in, scores_s, boxes_s, nvp);
  k_sup<<<dim3(WMAX, (N_ANCH + 255) / 256), dim3(256), 0, stream>>>(boxes_s, nvp, sup2);
  k_scan_out<<<dim3(1), dim3(NT), 0, stream>>>(scores_s, boxes_s, sup2, nvp, out);
}